// Round 1
// baseline (362.367 us; speedup 1.0000x reference)
//
#include <hip/hip_runtime.h>
#include <math.h>

// Problem constants (from setup_inputs): B=8, coarse [8,1024,3], fine [8,8192,3],
// gt [8,3,8192] (channel-first), alpha scalar. Output: (loss, loss_coarse, loss_fine).
#define B_SZ 8
#define NF 8192
#define NC 1024
#define NG 8192
#define TPB 256
#define QPT 4               // queries per thread
#define QPB (TPB * QPT)     // 1024 queries per block
#define TILE 256            // targets staged in LDS per iteration

// Merged block ranges (one launch so all 4 directions overlap on the chip):
// [0,64)    fine  -> gt      (8 blocks/batch * 8 batches)  -> ws[0]
// [64,128)  gt    -> fine                                  -> ws[0]
// [128,192) gt    -> coarse                                -> ws[1]
// [192,200) coarse-> gt      (1 block/batch)               -> ws[1]

__global__ __launch_bounds__(TPB) void chamfer_kernel(
    const float* __restrict__ coarse, const float* __restrict__ fine,
    const float* __restrict__ gt, float* __restrict__ ws)
{
    __shared__ __align__(16) float sx[TILE];
    __shared__ __align__(16) float sy[TILE];
    __shared__ __align__(16) float sz[TILE];
    __shared__ __align__(16) float ss[TILE];
    __shared__ float red[TPB / 64];

    const int bid = blockIdx.x;
    const float* q; const float* t;
    int Nq, Nt; bool qcf, tcf; float scale; int accIdx; int batch, qblk;

    if (bid < 64) {            // fine -> gt
        q = fine; t = gt; Nq = NF; Nt = NG; qcf = false; tcf = true;
        scale = 1.0f / (B_SZ * NF); accIdx = 0;
        batch = bid >> 3; qblk = bid & 7;
    } else if (bid < 128) {    // gt -> fine
        q = gt; t = fine; Nq = NG; Nt = NF; qcf = true; tcf = false;
        scale = 1.0f / (B_SZ * NG); accIdx = 0;
        int r = bid - 64; batch = r >> 3; qblk = r & 7;
    } else if (bid < 192) {    // gt -> coarse
        q = gt; t = coarse; Nq = NG; Nt = NC; qcf = true; tcf = false;
        scale = 1.0f / (B_SZ * NG); accIdx = 1;
        int r = bid - 128; batch = r >> 3; qblk = r & 7;
    } else {                   // coarse -> gt
        q = coarse; t = gt; Nq = NC; Nt = NG; qcf = false; tcf = true;
        scale = 1.0f / (B_SZ * NC); accIdx = 1;
        batch = bid - 192; qblk = 0;
    }

    const int tid = threadIdx.x;

    // Load QPT query points; pre-scale by -2 and keep ||q||^2 for the epilogue.
    float ax[QPT], ay[QPT], az[QPT], qs2[QPT], m[QPT];
#pragma unroll
    for (int k = 0; k < QPT; k++) {
        const int qi = qblk * QPB + k * TPB + tid;
        float x, y, z;
        if (qcf) {
            x = q[(size_t)(batch * 3 + 0) * Nq + qi];
            y = q[(size_t)(batch * 3 + 1) * Nq + qi];
            z = q[(size_t)(batch * 3 + 2) * Nq + qi];
        } else {
            const float* p = q + ((size_t)batch * Nq + qi) * 3;
            x = p[0]; y = p[1]; z = p[2];
        }
        qs2[k] = x * x + y * y + z * z;
        ax[k] = -2.0f * x; ay[k] = -2.0f * y; az[k] = -2.0f * z;
        m[k] = INFINITY;
    }

    for (int tile = 0; tile < Nt; tile += TILE) {
        const int j = tile + tid;
        float x, y, z;
        if (tcf) {
            x = t[(size_t)(batch * 3 + 0) * Nt + j];
            y = t[(size_t)(batch * 3 + 1) * Nt + j];
            z = t[(size_t)(batch * 3 + 2) * Nt + j];
        } else {
            const float* p = t + ((size_t)batch * Nt + j) * 3;
            x = p[0]; y = p[1]; z = p[2];
        }
        __syncthreads();   // previous tile fully consumed before overwrite
        sx[tid] = x; sy[tid] = y; sz[tid] = z; ss[tid] = x * x + y * y + z * z;
        __syncthreads();

#pragma unroll 2
        for (int jj = 0; jj < TILE; jj += 4) {
            // wave-uniform addresses -> LDS broadcast, conflict-free
            const float4 vx = *(const float4*)&sx[jj];
            const float4 vy = *(const float4*)&sy[jj];
            const float4 vz = *(const float4*)&sz[jj];
            const float4 vs = *(const float4*)&ss[jj];
#pragma unroll
            for (int k = 0; k < QPT; k++) {
                // d_j = ||t_j||^2 - 2 q.t_j   (||q||^2 added after the min)
                float d0 = fmaf(ax[k], vx.x, fmaf(ay[k], vy.x, fmaf(az[k], vz.x, vs.x)));
                float d1 = fmaf(ax[k], vx.y, fmaf(ay[k], vy.y, fmaf(az[k], vz.y, vs.y)));
                float d2 = fmaf(ax[k], vx.z, fmaf(ay[k], vy.z, fmaf(az[k], vz.z, vs.z)));
                float d3 = fmaf(ax[k], vx.w, fmaf(ay[k], vy.w, fmaf(az[k], vz.w, vs.w)));
                m[k] = fminf(m[k], fminf(fminf(d0, d1), fminf(d2, d3)));
            }
        }
    }

    float s = 0.0f;
#pragma unroll
    for (int k = 0; k < QPT; k++) s += m[k] + qs2[k];

    // wave-64 reduction, then cross-wave via LDS
    for (int off = 32; off > 0; off >>= 1) s += __shfl_down(s, off);
    if ((tid & 63) == 0) red[tid >> 6] = s;
    __syncthreads();
    if (tid == 0) {
        const float bs = red[0] + red[1] + red[2] + red[3];
        atomicAdd(&ws[accIdx], bs * scale);
    }
}

__global__ void finalize_kernel(const float* __restrict__ ws,
                                const float* __restrict__ alpha,
                                float* __restrict__ out)
{
    const float lf = ws[0], lc = ws[1];
    out[0] = lc + alpha[0] * lf;   // loss
    out[1] = lc;                   // loss_coarse
    out[2] = lf;                   // loss_fine
}

extern "C" void kernel_launch(void* const* d_in, const int* in_sizes, int n_in,
                              void* d_out, int out_size, void* d_ws, size_t ws_size,
                              hipStream_t stream) {
    const float* coarse = (const float*)d_in[0];
    const float* fine   = (const float*)d_in[1];
    const float* gt     = (const float*)d_in[2];
    const float* alpha  = (const float*)d_in[3];
    float* out = (float*)d_out;
    float* ws  = (float*)d_ws;

    hipMemsetAsync(ws, 0, 2 * sizeof(float), stream);
    chamfer_kernel<<<200, TPB, 0, stream>>>(coarse, fine, gt, ws);
    finalize_kernel<<<1, 1, 0, stream>>>(ws, alpha, out);
}

// Round 2
// 173.102 us; speedup vs baseline: 2.0934x; 2.0934x over previous
//
#include <hip/hip_runtime.h>
#include <math.h>

// Chamfer loss: B=8, coarse [8,1024,3], fine [8,8192,3], gt [8,3,8192] (channel-first).
// Output: (loss, loss_coarse, loss_fine).
//
// Strategy: split BOTH queries and targets so every block does a uniform
// 1024q x 1024t chunk -> 1152 balanced blocks (~4.5/CU) for latency hiding.
// Partial mins across target slices combine via uint atomicMin (values are
// full squared distances, >= 0, so IEEE order == uint order).
#define B_SZ 8
#define NF 8192
#define NC 1024
#define NG 8192
#define TPB 256
#define QPT 4               // queries per thread
#define QPB (TPB * QPT)     // 1024 queries per block
#define TILE 256            // targets staged in LDS per iteration
#define TSLICE 1024         // targets per block (4 tiles)

// ws layout (floats): [0,65536)   fine->gt per-query min   (fine loss)
//                     [65536,131072)  gt->fine per-query min (fine loss)
//                     [131072,196608) gt->coarse per-query min (coarse loss)
//                     [196608,204800) coarse->gt per-query min (coarse loss)
//                     [204800]=acc_fine  [204801]=acc_coarse
#define NMIN 204800

__global__ __launch_bounds__(256) void fill_kernel(unsigned int* __restrict__ ws) {
    const int i = blockIdx.x * 256 + threadIdx.x;
    if (i < NMIN) ws[i] = 0x7F800000u;          // +inf
    if (i < 2) ws[NMIN + i] = 0u;               // float 0.0
}

// Block map (heavy uniform work, 1152 blocks):
// [0,512)     fine->gt  : batch=b/64, qblk=(b%64)/8, tslice=b%8   -> region 0
// [512,1024)  gt->fine  : same decode                             -> region 1
// [1024,1088) coarse->gt: batch=r/8, tslice=r%8, qblk=0           -> region 3
// [1088,1152) gt->coarse: batch=r/8, qblk=r%8, tslice=0           -> region 2
__global__ __launch_bounds__(TPB) void chamfer_kernel(
    const float* __restrict__ coarse, const float* __restrict__ fine,
    const float* __restrict__ gt, unsigned int* __restrict__ wsmin)
{
    __shared__ __align__(16) float sx[TILE];
    __shared__ __align__(16) float sy[TILE];
    __shared__ __align__(16) float sz[TILE];
    __shared__ __align__(16) float ss[TILE];

    const int bid = blockIdx.x;
    const float* q; const float* t;
    int Nq, Nt; bool qcf, tcf; int batch, qblk, tslice; int qbase;

    if (bid < 512) {              // fine -> gt
        q = fine; t = gt; Nq = NF; Nt = NG; qcf = false; tcf = true;
        batch = bid >> 6; qblk = (bid >> 3) & 7; tslice = bid & 7;
        qbase = 0 + batch * NF;
    } else if (bid < 1024) {      // gt -> fine
        const int r = bid - 512;
        q = gt; t = fine; Nq = NG; Nt = NF; qcf = true; tcf = false;
        batch = r >> 6; qblk = (r >> 3) & 7; tslice = r & 7;
        qbase = 65536 + batch * NG;
    } else if (bid < 1088) {      // coarse -> gt
        const int r = bid - 1024;
        q = coarse; t = gt; Nq = NC; Nt = NG; qcf = false; tcf = true;
        batch = r >> 3; tslice = r & 7; qblk = 0;
        qbase = 196608 + batch * NC;
    } else {                      // gt -> coarse
        const int r = bid - 1088;
        q = gt; t = coarse; Nq = NG; Nt = NC; qcf = true; tcf = false;
        batch = r >> 3; qblk = r & 7; tslice = 0;
        qbase = 131072 + batch * NG;
    }

    const int tid = threadIdx.x;
    const int t0 = tslice * TSLICE;

    float ax[QPT], ay[QPT], az[QPT], qs2[QPT], m[QPT];
#pragma unroll
    for (int k = 0; k < QPT; k++) {
        const int qi = qblk * QPB + k * TPB + tid;
        float x, y, z;
        if (qcf) {
            x = q[(size_t)(batch * 3 + 0) * Nq + qi];
            y = q[(size_t)(batch * 3 + 1) * Nq + qi];
            z = q[(size_t)(batch * 3 + 2) * Nq + qi];
        } else {
            const float* p = q + ((size_t)batch * Nq + qi) * 3;
            x = p[0]; y = p[1]; z = p[2];
        }
        qs2[k] = x * x + y * y + z * z;
        ax[k] = -2.0f * x; ay[k] = -2.0f * y; az[k] = -2.0f * z;
        m[k] = INFINITY;
    }

    for (int tile = 0; tile < TSLICE; tile += TILE) {
        const int j = t0 + tile + tid;
        float x, y, z;
        if (tcf) {
            x = t[(size_t)(batch * 3 + 0) * Nt + j];
            y = t[(size_t)(batch * 3 + 1) * Nt + j];
            z = t[(size_t)(batch * 3 + 2) * Nt + j];
        } else {
            const float* p = t + ((size_t)batch * Nt + j) * 3;
            x = p[0]; y = p[1]; z = p[2];
        }
        __syncthreads();   // previous tile fully consumed before overwrite
        sx[tid] = x; sy[tid] = y; sz[tid] = z; ss[tid] = x * x + y * y + z * z;
        __syncthreads();

#pragma unroll 2
        for (int jj = 0; jj < TILE; jj += 4) {
            // wave-uniform addresses -> LDS broadcast, conflict-free
            const float4 vx = *(const float4*)&sx[jj];
            const float4 vy = *(const float4*)&sy[jj];
            const float4 vz = *(const float4*)&sz[jj];
            const float4 vs = *(const float4*)&ss[jj];
#pragma unroll
            for (int k = 0; k < QPT; k++) {
                // d_j = ||t_j||^2 - 2 q.t_j   (||q||^2 added after the min)
                float d0 = fmaf(ax[k], vx.x, fmaf(ay[k], vy.x, fmaf(az[k], vz.x, vs.x)));
                float d1 = fmaf(ax[k], vx.y, fmaf(ay[k], vy.y, fmaf(az[k], vz.y, vs.y)));
                float d2 = fmaf(ax[k], vx.z, fmaf(ay[k], vy.z, fmaf(az[k], vz.z, vs.z)));
                float d3 = fmaf(ax[k], vx.w, fmaf(ay[k], vy.w, fmaf(az[k], vz.w, vs.w)));
                m[k] = fminf(m[k], fminf(fminf(d0, d1), fminf(d2, d3)));
            }
        }
    }

#pragma unroll
    for (int k = 0; k < QPT; k++) {
        const int qi = qblk * QPB + k * TPB + tid;
        const float d = m[k] + qs2[k];   // full ||q-t||^2 >= 0
        atomicMin(&wsmin[qbase + qi], __float_as_uint(d));
    }
}

// Sum the per-query mins into the two direction accumulators.
__global__ __launch_bounds__(256) void reduce_kernel(const unsigned int* __restrict__ wsmin,
                                                     float* __restrict__ acc)
{
    __shared__ float red0[4], red1[4];
    float s0 = 0.0f, s1 = 0.0f;
    for (int i = blockIdx.x * 256 + threadIdx.x; i < NMIN; i += gridDim.x * 256) {
        const float v = __uint_as_float(wsmin[i]);
        if (i < 131072) s0 += v; else s1 += v;
    }
    for (int off = 32; off > 0; off >>= 1) {
        s0 += __shfl_down(s0, off);
        s1 += __shfl_down(s1, off);
    }
    const int tid = threadIdx.x;
    if ((tid & 63) == 0) { red0[tid >> 6] = s0; red1[tid >> 6] = s1; }
    __syncthreads();
    if (tid == 0) {
        atomicAdd(&acc[0], red0[0] + red0[1] + red0[2] + red0[3]);
        atomicAdd(&acc[1], red1[0] + red1[1] + red1[2] + red1[3]);
    }
}

__global__ void finalize_kernel(const float* __restrict__ acc,
                                const float* __restrict__ alpha,
                                float* __restrict__ out)
{
    // region scales: fine dirs are each mean over 65536 values; coarse dirs:
    // gt->coarse over 65536, coarse->gt over 8192. Regions 2+3 were summed
    // together into acc[1]; their scales differ, so reduce handles it... they
    // don't — so finalize uses the split sums below instead.
    const float lf = acc[0] * (1.0f / 65536.0f);
    const float lc = acc[1];
    out[0] = lc + alpha[0] * lf;
    out[1] = lc;
    out[2] = lf;
}

// NOTE: regions 2 (gt->coarse, 65536 values, scale 1/65536) and 3 (coarse->gt,
// 8192 values, scale 1/8192) have different scales, so reduce_kernel must
// scale before accumulating. Done here via a second pass variant:
__global__ __launch_bounds__(256) void reduce_kernel2(const unsigned int* __restrict__ wsmin,
                                                      float* __restrict__ acc)
{
    __shared__ float red0[4], red1[4];
    float s0 = 0.0f, s1 = 0.0f;
    for (int i = blockIdx.x * 256 + threadIdx.x; i < NMIN; i += gridDim.x * 256) {
        const float v = __uint_as_float(wsmin[i]);
        if (i < 131072)      s0 += v * (1.0f / 65536.0f);   // fine: both dirs mean over B*8192
        else if (i < 196608) s1 += v * (1.0f / 65536.0f);   // gt->coarse: mean over B*8192
        else                 s1 += v * (1.0f / 8192.0f);    // coarse->gt: mean over B*1024
    }
    for (int off = 32; off > 0; off >>= 1) {
        s0 += __shfl_down(s0, off);
        s1 += __shfl_down(s1, off);
    }
    const int tid = threadIdx.x;
    if ((tid & 63) == 0) { red0[tid >> 6] = s0; red1[tid >> 6] = s1; }
    __syncthreads();
    if (tid == 0) {
        atomicAdd(&acc[0], red0[0] + red0[1] + red0[2] + red0[3]);
        atomicAdd(&acc[1], red1[0] + red1[1] + red1[2] + red1[3]);
    }
}

__global__ void finalize_kernel2(const float* __restrict__ acc,
                                 const float* __restrict__ alpha,
                                 float* __restrict__ out)
{
    const float lf = acc[0];
    const float lc = acc[1];
    out[0] = lc + alpha[0] * lf;
    out[1] = lc;
    out[2] = lf;
}

extern "C" void kernel_launch(void* const* d_in, const int* in_sizes, int n_in,
                              void* d_out, int out_size, void* d_ws, size_t ws_size,
                              hipStream_t stream) {
    const float* coarse = (const float*)d_in[0];
    const float* fine   = (const float*)d_in[1];
    const float* gt     = (const float*)d_in[2];
    const float* alpha  = (const float*)d_in[3];
    float* out = (float*)d_out;
    unsigned int* wsmin = (unsigned int*)d_ws;
    float* acc = (float*)d_ws + NMIN;

    fill_kernel<<<(NMIN + 2 + 255) / 256, 256, 0, stream>>>(wsmin);
    chamfer_kernel<<<1152, TPB, 0, stream>>>(coarse, fine, gt, wsmin);
    reduce_kernel2<<<256, 256, 0, stream>>>(wsmin, acc);
    finalize_kernel2<<<1, 1, 0, stream>>>(acc, alpha, out);
}